// Round 8
// baseline (149.319 us; speedup 1.0000x reference)
//
#include <hip/hip_runtime.h>
#include <hip/hip_bf16.h>

#define S_LEN 2048
#define NH 32
#define D_DIM 128
#define LAST_Q 64
#define SCALE_F 0.08838834764831845f
#define QSCALE (0.08838834764831845f * 1.4426950408889634f)  // scale * log2(e)
#define RESCALE_THR 11.54f

typedef __attribute__((ext_vector_type(8))) short bf16x8;
typedef __attribute__((ext_vector_type(4))) float f32x4;
typedef unsigned long long u64;
typedef unsigned int u32;
typedef unsigned short u16;

static __device__ __forceinline__ u16 f32_bf16(float f) {
  u32 u = __float_as_uint(f);
  u32 r = (u + 0x7FFFu + ((u >> 16) & 1u)) >> 16;
  return (u16)r;
}

static __device__ __forceinline__ u32 cvt_pk_bf16(float lo, float hi) {
  u32 r;
  asm("v_cvt_pk_bf16_f32 %0, %1, %2" : "=v"(r) : "v"(lo), "v"(hi));
  return r;
}

// ---------------- Stage 0+1a merged: conv (even blocks) + est (odd blocks) ----------------
// conv: preconvert to PRE-SWIZZLED bf16 kpre/vpre (as R7). est: f32 causal est scores.
// Memory-bound conv overlaps VALU-bound est across CUs.
__global__ __launch_bounds__(256) void conv_est_kernel(const float* __restrict__ k,
                                                       const float* __restrict__ v,
                                                       const float* __restrict__ q,
                                                       u16* __restrict__ kpre,
                                                       u16* __restrict__ vpre,
                                                       float* __restrict__ scores) {
  __shared__ char smem[18432];
  int bid = blockIdx.x;
  int b = bid >> 1;
  int tid = threadIdx.x;
  if ((bid & 1) == 0) {
    // ---- conv path ----
    int t = b & 31, h = b >> 5;
    int c0 = t * 64;
    u16 (*Vb)[136] = (u16(*)[136])smem;
    for (int i = tid; i < 512; i += 256) {
      int r = i >> 3, s = i & 7;
      const float* srcp = v + ((size_t)(h * S_LEN + c0 + r)) * D_DIM + s * 16;
      float4 f0 = *(const float4*)(srcp);
      float4 f1 = *(const float4*)(srcp + 4);
      float4 f2 = *(const float4*)(srcp + 8);
      float4 f3 = *(const float4*)(srcp + 12);
      bf16x8 t0, t1;
      t0[0] = (short)f32_bf16(f0.x); t0[1] = (short)f32_bf16(f0.y);
      t0[2] = (short)f32_bf16(f0.z); t0[3] = (short)f32_bf16(f0.w);
      t0[4] = (short)f32_bf16(f1.x); t0[5] = (short)f32_bf16(f1.y);
      t0[6] = (short)f32_bf16(f1.z); t0[7] = (short)f32_bf16(f1.w);
      t1[0] = (short)f32_bf16(f2.x); t1[1] = (short)f32_bf16(f2.y);
      t1[2] = (short)f32_bf16(f2.z); t1[3] = (short)f32_bf16(f2.w);
      t1[4] = (short)f32_bf16(f3.x); t1[5] = (short)f32_bf16(f3.y);
      t1[6] = (short)f32_bf16(f3.z); t1[7] = (short)f32_bf16(f3.w);
      *(bf16x8*)&Vb[r][s * 16] = t0;
      *(bf16x8*)&Vb[r][s * 16 + 8] = t1;
    }
    u16* kp = kpre + (size_t)h * 262144 + (size_t)t * 8192;
#pragma unroll
    for (int j = 0; j < 4; ++j) {
      int p = j * 256 + tid;
      int r = p >> 4;
      int g = (p & 15) ^ (r & 15);
      const float* srcp = k + ((size_t)(h * S_LEN + c0 + r)) * D_DIM + g * 8;
      float4 a = *(const float4*)srcp;
      float4 bb = *(const float4*)(srcp + 4);
      bf16x8 o;
      o[0] = (short)f32_bf16(a.x); o[1] = (short)f32_bf16(a.y);
      o[2] = (short)f32_bf16(a.z); o[3] = (short)f32_bf16(a.w);
      o[4] = (short)f32_bf16(bb.x); o[5] = (short)f32_bf16(bb.y);
      o[6] = (short)f32_bf16(bb.z); o[7] = (short)f32_bf16(bb.w);
      *(bf16x8*)(kp + p * 8) = o;
    }
    __syncthreads();
    u16* vp = vpre + (size_t)h * 262144 + (size_t)t * 8192;
#pragma unroll
    for (int j = 0; j < 4; ++j) {
      int p = j * 256 + tid;
      int d = p >> 3;
      int cb = (p & 7) ^ (d & 7);
      bf16x8 g;
#pragma unroll
      for (int e = 0; e < 8; ++e) g[e] = (short)Vb[cb * 8 + e][d];
      *(bf16x8*)(vp + p * 8) = g;
    }
  } else {
    // ---- est path ----
    int cc = b & 31, h = b >> 5;
    float (*Qs)[36] = (float(*)[36])smem;
    float (*Ks)[36] = (float(*)[36])(smem + 9216);
    int ty = tid >> 4, tx = tid & 15;
    float acc[4][4];
#pragma unroll
    for (int i = 0; i < 4; ++i)
#pragma unroll
      for (int j = 0; j < 4; ++j) acc[i][j] = 0.f;
    const float* qbase = q + ((size_t)h * S_LEN + (S_LEN - LAST_Q)) * D_DIM;
    const float* kbase = k + ((size_t)h * S_LEN + cc * 64) * D_DIM;
    for (int dc = 0; dc < 4; ++dc) {
      __syncthreads();
      for (int i = tid; i < 512; i += 256) {
        int r = i >> 3, s = i & 7;
        float4 a = *(const float4*)(qbase + (size_t)r * D_DIM + dc * 32 + s * 4);
        *(float4*)&Qs[r][s * 4] = a;
        float4 bb = *(const float4*)(kbase + (size_t)r * D_DIM + dc * 32 + s * 4);
        *(float4*)&Ks[r][s * 4] = bb;
      }
      __syncthreads();
#pragma unroll
      for (int d4 = 0; d4 < 8; ++d4) {
        float4 qv[4], kv[4];
#pragma unroll
        for (int i = 0; i < 4; ++i) qv[i] = *(const float4*)&Qs[ty + 16 * i][d4 * 4];
#pragma unroll
        for (int j = 0; j < 4; ++j) kv[j] = *(const float4*)&Ks[tx + 16 * j][d4 * 4];
#pragma unroll
        for (int i = 0; i < 4; ++i)
#pragma unroll
          for (int j = 0; j < 4; ++j)
            acc[i][j] += qv[i].x * kv[j].x + qv[i].y * kv[j].y + qv[i].z * kv[j].z + qv[i].w * kv[j].w;
      }
    }
#pragma unroll
    for (int i = 0; i < 4; ++i) {
      int rl = ty + 16 * i;
      int rg = (S_LEN - LAST_Q) + rl;
#pragma unroll
      for (int j = 0; j < 4; ++j) {
        int cg = cc * 64 + tx + 16 * j;
        float vv = (cg <= rg) ? acc[i][j] * SCALE_F : -1e30f;
        scores[((size_t)h * LAST_Q + rl) * S_LEN + cg] = vv;
      }
    }
  }
}

// ---------------- standalone est (fallback when no workspace) ----------------
__global__ __launch_bounds__(256) void est_kernel(const float* __restrict__ q,
                                                  const float* __restrict__ k,
                                                  float* __restrict__ scores) {
  int cc = blockIdx.x;
  int h = blockIdx.y;
  int tid = threadIdx.x;
  int ty = tid >> 4, tx = tid & 15;
  __shared__ float Qs[64][36];
  __shared__ float Ks[64][36];
  float acc[4][4];
#pragma unroll
  for (int i = 0; i < 4; ++i)
#pragma unroll
    for (int j = 0; j < 4; ++j) acc[i][j] = 0.f;
  const float* qbase = q + ((size_t)h * S_LEN + (S_LEN - LAST_Q)) * D_DIM;
  const float* kbase = k + ((size_t)h * S_LEN + cc * 64) * D_DIM;
  for (int dc = 0; dc < 4; ++dc) {
    __syncthreads();
    for (int i = tid; i < 512; i += 256) {
      int r = i >> 3, s = i & 7;
      float4 a = *(const float4*)(qbase + (size_t)r * D_DIM + dc * 32 + s * 4);
      *(float4*)&Qs[r][s * 4] = a;
      float4 b = *(const float4*)(kbase + (size_t)r * D_DIM + dc * 32 + s * 4);
      *(float4*)&Ks[r][s * 4] = b;
    }
    __syncthreads();
#pragma unroll
    for (int d4 = 0; d4 < 8; ++d4) {
      float4 qv[4], kv[4];
#pragma unroll
      for (int i = 0; i < 4; ++i) qv[i] = *(const float4*)&Qs[ty + 16 * i][d4 * 4];
#pragma unroll
      for (int j = 0; j < 4; ++j) kv[j] = *(const float4*)&Ks[tx + 16 * j][d4 * 4];
#pragma unroll
      for (int i = 0; i < 4; ++i)
#pragma unroll
        for (int j = 0; j < 4; ++j)
          acc[i][j] += qv[i].x * kv[j].x + qv[i].y * kv[j].y + qv[i].z * kv[j].z + qv[i].w * kv[j].w;
    }
  }
#pragma unroll
  for (int i = 0; i < 4; ++i) {
    int rl = ty + 16 * i;
    int rg = (S_LEN - LAST_Q) + rl;
#pragma unroll
    for (int j = 0; j < 4; ++j) {
      int cg = cc * 64 + tx + 16 * j;
      float vv = (cg <= rg) ? acc[i][j] * SCALE_F : -1e30f;
      scores[((size_t)h * LAST_Q + rl) * S_LEN + cg] = vv;
    }
  }
}

// ---------------- Stage 1b: softmax partials (grid 32 x 16, 4 rows each) ----------------
__global__ __launch_bounds__(256) void soft_partial_kernel(const float* __restrict__ scores,
                                                           float* __restrict__ part) {
  int h = blockIdx.x, rg = blockIdx.y;
  int tid = threadIdx.x;
  int wave = tid >> 6, lane = tid & 63;
  __shared__ float vs[2048];
  __shared__ float ss[2048];
  __shared__ float red[4];
  int i0 = tid * 8;
#pragma unroll
  for (int e = 0; e < 8; ++e) { vs[i0 + e] = 0.f; ss[i0 + e] = 0.f; }
  for (int rr = 0; rr < 4; ++rr) {
    int r = rg * 4 + rr;
    const float* sp = scores + ((size_t)h * LAST_Q + r) * S_LEN;
    float4 a = *(const float4*)(sp + i0);
    float4 b = *(const float4*)(sp + i0 + 4);
    float x[8] = {a.x, a.y, a.z, a.w, b.x, b.y, b.z, b.w};
    float wm = -1e30f;
#pragma unroll
    for (int e = 0; e < 8; ++e) wm = fmaxf(wm, x[e]);
#pragma unroll
    for (int mk = 1; mk < 64; mk <<= 1) wm = fmaxf(wm, __shfl_xor(wm, mk, 64));
    __syncthreads();
    if (lane == 0) red[wave] = wm;
    __syncthreads();
    float m = fmaxf(fmaxf(red[0], red[1]), fmaxf(red[2], red[3]));
    float psum = 0.f;
#pragma unroll
    for (int e = 0; e < 8; ++e) { x[e] = __expf(x[e] - m); psum += x[e]; }
#pragma unroll
    for (int mk = 1; mk < 64; mk <<= 1) psum += __shfl_xor(psum, mk, 64);
    __syncthreads();
    if (lane == 0) red[wave] = psum;
    __syncthreads();
    float inv = 1.f / (red[0] + red[1] + red[2] + red[3]);
    int rgl = (S_LEN - LAST_Q) + r;
#pragma unroll
    for (int e = 0; e < 8; ++e) {
      float p = x[e] * inv;
      int i = i0 + e;
      vs[i] += p;
      int d = rgl - i;
      if (d >= 0) ss[d] += p;
    }
  }
  __syncthreads();
  float* pb = part + ((size_t)(h * 16 + rg)) * 4096;
#pragma unroll
  for (int e = 0; e < 8; ++e) { pb[i0 + e] = vs[i0 + e]; pb[2048 + i0 + e] = ss[i0 + e]; }
}

// ---------------- Stage 1c: fused reduce + top-k -> bitmasks ----------------
__global__ __launch_bounds__(256) void topk_kernel(const float* __restrict__ part,
                                                   u64* __restrict__ vbits,
                                                   u64* __restrict__ sbits) {
  int h = blockIdx.x;
  int which = blockIdx.y;
  u64* dst = which ? (sbits + h * 32) : (vbits + h * 32);
  u32 K = which ? 512u : 256u;
  int ninf = which ? 64 : 4;
  int tid = threadIdx.x;
  int lane = tid & 63, wid = tid >> 6;
  __shared__ u32 keys[2048];
  __shared__ u32 hist[256];
  __shared__ u32 wpart[4];
  __shared__ u32 sh_pref, sh_kth;
  __shared__ u64 mbw[32];
  int i0 = tid * 8;
  float accv[8] = {0.f, 0.f, 0.f, 0.f, 0.f, 0.f, 0.f, 0.f};
  for (int rg = 0; rg < 16; ++rg) {
    const float* pp = part + ((size_t)(h * 16 + rg)) * 4096 + which * 2048 + i0;
    float4 a = *(const float4*)pp;
    float4 b = *(const float4*)(pp + 4);
    accv[0] += a.x; accv[1] += a.y; accv[2] += a.z; accv[3] += a.w;
    accv[4] += b.x; accv[5] += b.y; accv[6] += b.z; accv[7] += b.w;
  }
#pragma unroll
  for (int e = 0; e < 8; ++e) {
    int i = i0 + e;
    keys[i] = (i < ninf) ? 0x7F800000u : __float_as_uint(accv[e]);
  }
  __syncthreads();
  u32 prefix = 0;
  u32 kth = K;
  for (int shift = 24; shift >= 0; shift -= 8) {
    hist[tid] = 0;
    __syncthreads();
#pragma unroll
    for (int e = 0; e < 8; ++e) {
      u32 kk = keys[i0 + e];
      if (shift == 24 || (kk >> (shift + 8)) == (prefix >> (shift + 8)))
        atomicAdd(&hist[(kk >> shift) & 255], 1u);
    }
    __syncthreads();
    u32 v = hist[tid];
    u32 x = v;
#pragma unroll
    for (int off = 1; off < 64; off <<= 1) {
      u32 o = __shfl_up(x, off, 64);
      if (lane >= off) x += o;
    }
    if (lane == 63) wpart[wid] = x;
    __syncthreads();
    u32 base = 0;
    for (int w2 = 0; w2 < wid; ++w2) base += wpart[w2];
    u32 T = wpart[0] + wpart[1] + wpart[2] + wpart[3];
    u32 Pincl = x + base;
    u32 Sb = T - Pincl + v;
    u32 Sn = T - Pincl;
    if (Sb >= kth && Sn < kth) {
      sh_pref = prefix | ((u32)tid << shift);
      sh_kth = kth - Sn;
    }
    __syncthreads();
    prefix = sh_pref;
    kth = sh_kth;
    __syncthreads();
  }
  u32 t = prefix;
  u32 cnt = 0;
#pragma unroll
  for (int e = 0; e < 8; ++e) cnt += (keys[i0 + e] == t) ? 1u : 0u;
  u32 x = cnt;
#pragma unroll
  for (int off = 1; off < 64; off <<= 1) {
    u32 o = __shfl_up(x, off, 64);
    if (lane >= off) x += o;
  }
  if (lane == 63) wpart[wid] = x;
  __syncthreads();
  u32 base = 0;
  for (int w2 = 0; w2 < wid; ++w2) base += wpart[w2];
  u32 exc = x + base - cnt;
  unsigned char myb = 0;
  u32 seen = 0;
#pragma unroll
  for (int e = 0; e < 8; ++e) {
    u32 kk = keys[i0 + e];
    bool in = (kk > t) || (kk == t && (exc + seen) < kth);
    if (kk == t) ++seen;
    myb |= (in ? 1u : 0u) << e;
  }
  ((unsigned char*)mbw)[tid] = myb;
  __syncthreads();
  if (tid < 32) dst[tid] = mbw[tid];
}

// ---------------- Stage 2: per-wave dual-qtile swapped-QK flash attention ----------------
// grid 512, 256 threads (4 waves x 16 q-rows x 2 qtiles). Every wave = exactly 33 tile-
// computes (qtiles idx & 31-idx) -> uniform wall. Head-grouped; split K/V DMA pipeline.
template <bool PRE>
__global__ __launch_bounds__(256, 2) void attn_kernel(const float* __restrict__ q,
                                                      const float* __restrict__ kk,
                                                      const float* __restrict__ vv,
                                                      const u16* __restrict__ kpre,
                                                      const u16* __restrict__ vpre,
                                                      const u64* __restrict__ vbits,
                                                      const u64* __restrict__ sbits,
                                                      float* __restrict__ out) {
  int bid = blockIdx.x;
  int u = bid & 255;
  int h = u & 31;
  int idx = ((u >> 5) & 7) + ((bid >> 8) << 3);  // 0..15; CU pair (bid,bid+256) shares h
  int qtA = idx, qtB = 31 - idx;
  int tid = threadIdx.x;
  int wave = tid >> 6, lane = tid & 63;
  int grp = lane >> 4, ln = lane & 15;

  __shared__ u16 Ks[8192];
  __shared__ u16 Vt[8192];
  __shared__ u64 smp[34];

  if (tid < 34) smp[tid] = (tid == 0 || tid == 33) ? 0ull : sbits[h * 32 + tid - 1];

  int q0A = qtA * 64 + wave * 16;
  int q0B = qtB * 64 + wave * 16;

  // Q fragments for both qtiles (QSCALE folded)
  bf16x8 qfA[4], qfB[4];
  {
    const float* qrowA = q + ((size_t)h * S_LEN + q0A + ln) * D_DIM;
    const float* qrowB = q + ((size_t)h * S_LEN + q0B + ln) * D_DIM;
#pragma unroll
    for (int ks = 0; ks < 4; ++ks) {
      const float* pA = qrowA + ks * 32 + grp * 8;
      const float* pB = qrowB + ks * 32 + grp * 8;
      float4 a = *(const float4*)pA;
      float4 b = *(const float4*)(pA + 4);
      bf16x8 f;
      f[0] = (short)f32_bf16(a.x * QSCALE); f[1] = (short)f32_bf16(a.y * QSCALE);
      f[2] = (short)f32_bf16(a.z * QSCALE); f[3] = (short)f32_bf16(a.w * QSCALE);
      f[4] = (short)f32_bf16(b.x * QSCALE); f[5] = (short)f32_bf16(b.y * QSCALE);
      f[6] = (short)f32_bf16(b.z * QSCALE); f[7] = (short)f32_bf16(b.w * QSCALE);
      qfA[ks] = f;
      a = *(const float4*)pB;
      b = *(const float4*)(pB + 4);
      f[0] = (short)f32_bf16(a.x * QSCALE); f[1] = (short)f32_bf16(a.y * QSCALE);
      f[2] = (short)f32_bf16(a.z * QSCALE); f[3] = (short)f32_bf16(a.w * QSCALE);
      f[4] = (short)f32_bf16(b.x * QSCALE); f[5] = (short)f32_bf16(b.y * QSCALE);
      f[6] = (short)f32_bf16(b.z * QSCALE); f[7] = (short)f32_bf16(b.w * QSCALE);
      qfB[ks] = f;
    }
  }
  f32x4 ofA[8], ofB[8];
#pragma unroll
  for (int i = 0; i < 8; ++i) {
    ofA[i] = (f32x4){0.f, 0.f, 0.f, 0.f};
    ofB[i] = (f32x4){0.f, 0.f, 0.f, 0.f};
  }
  float mrA = -1e30f, lsA = 0.f;
  float mrB = -1e30f, lsB = 0.f;

  // hoisted LDS fragment bases
  const int kb0 = (ln << 7) + (((0 + grp) ^ ln) << 3);
  const int kb1 = (ln << 7) + (((4 + grp) ^ ln) << 3);
  const int kb2 = (ln << 7) + (((8 + grp) ^ ln) << 3);
  const int kb3 = (ln << 7) + (((12 + grp) ^ ln) << 3);
  const int vb0 = (ln << 6) + (((0 + grp) ^ (ln & 7)) << 3);
  const int vb1 = (ln << 6) + (((4 + grp) ^ (ln & 7)) << 3);

  const u16* kp = kpre + (size_t)h * 262144;
  const u16* vp = vpre + (size_t)h * 262144;
  const float* kfb = kk + (size_t)h * S_LEN * D_DIM;
  const float* vfb = vv + (size_t)h * S_LEN * D_DIM;
  const u64* vwp = vbits + h * 32;
  int nt = qtB + 1;
  int sb_lane = (lane & 48) + ((lane & 48) >> 2);

  auto dma_k = [&](int t) {
    const u16* ksrc = kp + (size_t)t * 8192;
#pragma unroll
    for (int i = 0; i < 4; ++i) {
      int chunk = wave * 4 + i;
      __builtin_amdgcn_global_load_lds(
          (const __attribute__((address_space(1))) u32*)(const void*)(ksrc + (size_t)(chunk * 64 + lane) * 8),
          (__attribute__((address_space(3))) u32*)(void*)(&Ks[chunk * 512]), 16, 0, 0);
    }
  };
  auto dma_v = [&](int t) {
    const u16* vsrc = vp + (size_t)t * 8192;
#pragma unroll
    for (int i = 0; i < 4; ++i) {
      int chunk = wave * 4 + i;
      __builtin_amdgcn_global_load_lds(
          (const __attribute__((address_space(1))) u32*)(const void*)(vsrc + (size_t)(chunk * 64 + lane) * 8),
          (__attribute__((address_space(3))) u32*)(void*)(&Vt[chunk * 512]), 16, 0, 0);
    }
  };

  // per-qtile QK^T + softmax + mask + pack (writes pkw[8])
  auto qk_sm = [&](int c0, int q0w, const bf16x8* qf, f32x4* of, float& mr, float& ls,
                   u32* pkw, u64 vword) {
    f32x4 sfr[4];
    __builtin_amdgcn_s_setprio(1);
#pragma unroll
    for (int nb = 0; nb < 4; ++nb) {
      f32x4 acc = (f32x4){0.f, 0.f, 0.f, 0.f};
      acc = __builtin_amdgcn_mfma_f32_16x16x32_bf16(*(const bf16x8*)&Ks[kb0 + nb * 2048], qf[0], acc, 0, 0, 0);
      acc = __builtin_amdgcn_mfma_f32_16x16x32_bf16(*(const bf16x8*)&Ks[kb1 + nb * 2048], qf[1], acc, 0, 0, 0);
      acc = __builtin_amdgcn_mfma_f32_16x16x32_bf16(*(const bf16x8*)&Ks[kb2 + nb * 2048], qf[2], acc, 0, 0, 0);
      acc = __builtin_amdgcn_mfma_f32_16x16x32_bf16(*(const bf16x8*)&Ks[kb3 + nb * 2048], qf[3], acc, 0, 0, 0);
      sfr[nb] = acc;
    }
    __builtin_amdgcn_s_setprio(0);
    float tm = sfr[0][0];
#pragma unroll
    for (int nb = 0; nb < 4; ++nb)
#pragma unroll
      for (int jj = 0; jj < 4; ++jj) tm = fmaxf(tm, sfr[nb][jj]);
    tm = fmaxf(tm, __shfl_xor(tm, 16, 64));
    tm = fmaxf(tm, __shfl_xor(tm, 32, 64));
    if (__any(tm - mr > RESCALE_THR)) {
      float mn = fmaxf(mr, tm);
      float ex = __builtin_amdgcn_exp2f(mr - mn);
      mr = mn;
      ls *= ex;
      float e0 = __shfl(ex, sb_lane, 64);
      float e1 = __shfl(ex, sb_lane + 1, 64);
      float e2 = __shfl(ex, sb_lane + 2, 64);
      float e3 = __shfl(ex, sb_lane + 3, 64);
#pragma unroll
      for (int db = 0; db < 8; ++db) {
        of[db][0] *= e0; of[db][1] *= e1; of[db][2] *= e2; of[db][3] *= e3;
      }
    }
    int Cb = (q0w + ln) - c0 - (grp << 2);
    float rs = 0.f;
    if (c0 >= q0w - 48) {
#pragma unroll
      for (int nb = 0; nb < 4; ++nb) {
        float pv[4];
#pragma unroll
        for (int jj = 0; jj < 4; ++jj) {
          bool keep = (16 * nb + jj) <= Cb;
          float p = keep ? __builtin_amdgcn_exp2f(sfr[nb][jj] - mr) : 0.f;
          rs += p;
          pv[jj] = p;
        }
        pkw[nb * 2] = cvt_pk_bf16(pv[0], pv[1]);
        pkw[nb * 2 + 1] = cvt_pk_bf16(pv[2], pv[3]);
      }
    } else {
      int b0 = Cb - 63;
      int w0i = (b0 >> 6) + 1;
      int sh = b0 & 63;
      u64 lo = smp[w0i];
      u64 hi = smp[w0i + 1];
      u64 W = (sh == 0) ? lo : ((lo >> sh) | (hi << (64 - sh)));
#pragma unroll
      for (int nb = 0; nb < 4; ++nb) {
        u32 vn = (u32)(vword >> (16 * nb + 4 * grp)) & 0xFu;
        u32 sn = (u32)(W >> (60 - 16 * nb)) & 0xFu;
        float pv[4];
#pragma unroll
        for (int jj = 0; jj < 4; ++jj) {
          u32 keep = ((vn >> jj) | (sn >> (3 - jj))) & 1u;
          float p = keep ? __builtin_amdgcn_exp2f(sfr[nb][jj] - mr) : 0.f;
          rs += p;
          pv[jj] = p;
        }
        pkw[nb * 2] = cvt_pk_bf16(pv[0], pv[1]);
        pkw[nb * 2 + 1] = cvt_pk_bf16(pv[2], pv[3]);
      }
    }
    rs += __shfl_xor(rs, 16, 64);
    rs += __shfl_xor(rs, 32, 64);
    ls += rs;
  };

  auto pv_phase = [&](const u32* pkw, f32x4* of) {
#pragma unroll
    for (int ks2 = 0; ks2 < 2; ++ks2) {
      int sl0 = ln + ((lane & 16) << 1);
      int sl1 = sl0 + 16;
      u32 a0 = __shfl(pkw[ks2 * 4 + 0], sl0, 64);
      u32 a1 = __shfl(pkw[ks2 * 4 + 1], sl0, 64);
      u32 a2 = __shfl(pkw[ks2 * 4 + 0], sl1, 64);
      u32 a3 = __shfl(pkw[ks2 * 4 + 1], sl1, 64);
      u32 b0_ = __shfl(pkw[ks2 * 4 + 2], sl0, 64);
      u32 b1_ = __shfl(pkw[ks2 * 4 + 3], sl0, 64);
      u32 b2_ = __shfl(pkw[ks2 * 4 + 2], sl1, 64);
      u32 b3_ = __shfl(pkw[ks2 * 4 + 3], sl1, 64);
      bool hi2 = grp >= 2;
      union { u32 w[4]; bf16x8 v; } pu;
      pu.w[0] = hi2 ? b0_ : a0;
      pu.w[1] = hi2 ? b1_ : a1;
      pu.w[2] = hi2 ? b2_ : a2;
      pu.w[3] = hi2 ? b3_ : a3;
      int vb = ks2 ? vb1 : vb0;
      __builtin_amdgcn_s_setprio(1);
#pragma unroll
      for (int db = 0; db < 8; ++db) {
        bf16x8 vf = *(const bf16x8*)&Vt[vb + db * 1024];
        of[db] = __builtin_amdgcn_mfma_f32_16x16x32_bf16(pu.v, vf, of[db], 0, 0, 0);
      }
      __builtin_amdgcn_s_setprio(0);
    }
  };

  if constexpr (PRE) { dma_k(0); dma_v(0); }
  __syncthreads();  // drains prologue DMA + smp writes

  for (int t = 0; t < nt; ++t) {
    int c0 = t * 64;
    if constexpr (!PRE) {
      for (int i = tid; i < 512; i += 256) {
        int r = i >> 3, s2 = i & 7;
        const float* srcp = kfb + (size_t)(c0 + r) * D_DIM + s2 * 16;
        float4 f0 = *(const float4*)(srcp);
        float4 f1 = *(const float4*)(srcp + 4);
        float4 f2 = *(const float4*)(srcp + 8);
        float4 f3 = *(const float4*)(srcp + 12);
        bf16x8 t0, t1;
        t0[0] = (short)f32_bf16(f0.x); t0[1] = (short)f32_bf16(f0.y);
        t0[2] = (short)f32_bf16(f0.z); t0[3] = (short)f32_bf16(f0.w);
        t0[4] = (short)f32_bf16(f1.x); t0[5] = (short)f32_bf16(f1.y);
        t0[6] = (short)f32_bf16(f1.z); t0[7] = (short)f32_bf16(f1.w);
        t1[0] = (short)f32_bf16(f2.x); t1[1] = (short)f32_bf16(f2.y);
        t1[2] = (short)f32_bf16(f2.z); t1[3] = (short)f32_bf16(f2.w);
        t1[4] = (short)f32_bf16(f3.x); t1[5] = (short)f32_bf16(f3.y);
        t1[6] = (short)f32_bf16(f3.z); t1[7] = (short)f32_bf16(f3.w);
        int cb0 = s2 * 2, cb1 = s2 * 2 + 1;
        *(bf16x8*)&Ks[r * 128 + ((cb0 ^ (r & 15)) << 3)] = t0;
        *(bf16x8*)&Ks[r * 128 + ((cb1 ^ (r & 15)) << 3)] = t1;
      }
      for (int i = tid; i < 512; i += 256) {
        int r = i >> 3, s2 = i & 7;
        const float* srcp = vfb + (size_t)(c0 + r) * D_DIM + s2 * 16;
#pragma unroll
        for (int x = 0; x < 16; x += 4) {
          float4 f4 = *(const float4*)(srcp + x);
          int d0 = s2 * 16 + x;
          float vals[4] = {f4.x, f4.y, f4.z, f4.w};
#pragma unroll
          for (int y = 0; y < 4; ++y) {
            int d = d0 + y;
            Vt[d * 64 + (((r >> 3) ^ (d & 7)) << 3) + (r & 7)] = f32_bf16(vals[y]);
          }
        }
      }
      __syncthreads();
    }

    u64 vword = vwp[t];
    bool doA = (t <= qtA);
    u32 pkwB[8], pkwA[8];
    qk_sm(c0, q0B, qfB, ofB, mrB, lsB, pkwB, vword);
    if (doA) qk_sm(c0, q0A, qfA, ofA, mrA, lsA, pkwA, vword);

    // BAR_A: Ks reads done + V(t) landed; prefetch K(t+1)
    if constexpr (PRE) {
      __builtin_amdgcn_sched_barrier(0);
      asm volatile("s_waitcnt vmcnt(0)" ::: "memory");
      __builtin_amdgcn_s_barrier();
      if (t + 1 < nt) dma_k(t + 1);
    }

    pv_phase(pkwB, ofB);
    if (doA) pv_phase(pkwA, ofA);

    // BAR_B: Vt reads done; prefetch V(t+1); wait K(t+1); BAR_C
    if constexpr (PRE) {
      __builtin_amdgcn_sched_barrier(0);
      __builtin_amdgcn_s_barrier();
      if (t + 1 < nt) {
        dma_v(t + 1);
        asm volatile("s_waitcnt vmcnt(4)" ::: "memory");
      }
      __builtin_amdgcn_s_barrier();
    } else {
      __syncthreads();
    }
  }

  // ---- epilogue: both qtiles ----
  float invA = 1.f / lsA;
  float invB = 1.f / lsB;
  float a0 = __shfl(invA, sb_lane, 64);
  float a1 = __shfl(invA, sb_lane + 1, 64);
  float a2 = __shfl(invA, sb_lane + 2, 64);
  float a3 = __shfl(invA, sb_lane + 3, 64);
  float b0 = __shfl(invB, sb_lane, 64);
  float b1 = __shfl(invB, sb_lane + 1, 64);
  float b2 = __shfl(invB, sb_lane + 2, 64);
  float b3 = __shfl(invB, sb_lane + 3, 64);
  float* obA = out + ((size_t)h * S_LEN + q0A) * D_DIM;
  float* obB = out + ((size_t)h * S_LEN + q0B) * D_DIM;
#pragma unroll
  for (int db = 0; db < 8; ++db) {
    obA[(size_t)(grp * 4 + 0) * D_DIM + db * 16 + ln] = ofA[db][0] * a0;
    obA[(size_t)(grp * 4 + 1) * D_DIM + db * 16 + ln] = ofA[db][1] * a1;
    obA[(size_t)(grp * 4 + 2) * D_DIM + db * 16 + ln] = ofA[db][2] * a2;
    obA[(size_t)(grp * 4 + 3) * D_DIM + db * 16 + ln] = ofA[db][3] * a3;
    obB[(size_t)(grp * 4 + 0) * D_DIM + db * 16 + ln] = ofB[db][0] * b0;
    obB[(size_t)(grp * 4 + 1) * D_DIM + db * 16 + ln] = ofB[db][1] * b1;
    obB[(size_t)(grp * 4 + 2) * D_DIM + db * 16 + ln] = ofB[db][2] * b2;
    obB[(size_t)(grp * 4 + 3) * D_DIM + db * 16 + ln] = ofB[db][3] * b3;
  }
}

extern "C" void kernel_launch(void* const* d_in, const int* in_sizes, int n_in,
                              void* d_out, int out_size, void* d_ws, size_t ws_size,
                              hipStream_t stream) {
  const float* q = (const float*)d_in[0];
  const float* k = (const float*)d_in[1];
  const float* v = (const float*)d_in[2];
  float* out = (float*)d_out;
  float* scores = out;                 // [0, 4194304)
  float* part = out + 4194304;         // 512 * 4096 floats = [4194304, 6291456)
  u64* vbits = (u64*)d_ws;
  u64* sbits = vbits + 1024;
  const size_t PRE_NEED = 16384 + 2ull * 16777216;
  bool pre = ws_size >= PRE_NEED;
  u16* kpre = (u16*)((char*)d_ws + 16384);
  u16* vpre = kpre + 8388608;

  if (pre) {
    conv_est_kernel<<<2048, 256, 0, stream>>>(k, v, q, kpre, vpre, scores);
  } else {
    est_kernel<<<dim3(32, 32), 256, 0, stream>>>(q, k, scores);
  }
  soft_partial_kernel<<<dim3(32, 16), 256, 0, stream>>>(scores, part);
  topk_kernel<<<dim3(32, 2), 256, 0, stream>>>(part, vbits, sbits);
  if (pre)
    attn_kernel<true><<<512, 256, 0, stream>>>(q, k, v, kpre, vpre, vbits, sbits, out);
  else
    attn_kernel<false><<<512, 256, 0, stream>>>(q, k, v, kpre, vpre, vbits, sbits, out);
}